// Round 7
// baseline (664.589 us; speedup 1.0000x reference)
//
#include <hip/hip_runtime.h>
#include <float.h>

// HierarchicalLoss: total = 0.5*sum_l CE(out_l, targets[:,l]) + 0.5*sum_l (e-1)*mean(1-V_l[p_l,p_{l+1}])
// R7: single fused kernel. R6's wave-autonomous ce (no barriers, no LDS) +
// device-scope atomic completion counter: the LAST block reduces the 4096x8
// partials and writes the 3 outputs. Counter self-arms from the harness's
// 0xAA ws poison via atomicCAS (also correct if ws is zeroed instead).

#define NB 4096
#define GRID 3072

static constexpr float LOG2E = 1.4426950408889634f;
static constexpr float LN2   = 0.6931471805599453f;
static constexpr float E_M1  = 1.7182818284590452f;   // e - 1

__device__ __forceinline__ float hw_exp2(float x) { return __builtin_amdgcn_exp2f(x); }
__device__ __forceinline__ float hw_log2(float x) { return __builtin_amdgcn_logf(x); }

__device__ __forceinline__ float max4(float4 v) {
    return fmaxf(fmaxf(v.x, v.y), fmaxf(v.z, v.w));
}
__device__ __forceinline__ float sumexp4(float4 v, float M) {
    return hw_exp2((v.x - M) * LOG2E) + hw_exp2((v.y - M) * LOG2E)
         + hw_exp2((v.z - M) * LOG2E) + hw_exp2((v.w - M) * LOG2E);
}
__device__ __forceinline__ void online4(float4 v, float& m, float& s) {
    float mn = fmaxf(m, max4(v));
    s = s * hw_exp2((m - mn) * LOG2E) + sumexp4(v, mn);
    m = mn;
}
__device__ __forceinline__ void combine_ms(float& m, float& s, float m2, float s2) {
    float mn = fmaxf(m, m2);
    s = s * hw_exp2((m - mn) * LOG2E) + s2 * hw_exp2((m2 - mn) * LOG2E);
    m = mn;
}
__device__ __forceinline__ float wave_max(float v) {
    #pragma unroll
    for (int off = 32; off; off >>= 1) v = fmaxf(v, __shfl_xor(v, off));
    return v;
}
__device__ __forceinline__ float wave_sum(float v) {
    #pragma unroll
    for (int off = 32; off; off >>= 1) v += __shfl_xor(v, off);
    return v;
}

// ws layout: floats [0 .. 32767] = [row][8] {nll0..3, ok01, ok12, ok23, pad};
// uint at float-index 32768 = completion counter (poison-armed).
__global__ __launch_bounds__(256) void hier_loss_kernel(
    const float* __restrict__ o0, const float* __restrict__ o1,
    const float* __restrict__ o2, const float* __restrict__ o3,
    const int* __restrict__ targets,
    const int* __restrict__ p0, const int* __restrict__ p1,
    const int* __restrict__ p2, const int* __restrict__ p3,
    const int* __restrict__ v01, const int* __restrict__ v12,
    const int* __restrict__ v23, float* __restrict__ ws8,
    unsigned* __restrict__ cnt, float* __restrict__ out)
{
    const int gw   = (blockIdx.x << 2) | (threadIdx.x >> 6);  // global wave id
    const int lane = threadIdx.x & 63;

    if (gw < 4096) {
        // ---------- level 3: one wave = one row of 8192 ----------
        const int row = gw;
        const float4* r3 = (const float4*)(o3 + (size_t)row * 8192);

        int tgt = 0;
        if (lane == 0) tgt = targets[row * 4 + 3];

        float4 buf[8];
        #pragma unroll
        for (int j = 0; j < 8; j++) buf[j] = r3[lane + (j << 6)];

        float xt = 0.0f;
        if (lane == 0) xt = o3[(size_t)row * 8192 + tgt];

        float m[8], s[8];
        #pragma unroll
        for (int j = 0; j < 8; j++) { m[j] = -FLT_MAX; s[j] = 0.0f; }

        #pragma unroll
        for (int r = 0; r < 3; r++) {
            #pragma unroll
            for (int j = 0; j < 8; j++) {
                float4 v = buf[j];
                buf[j] = r3[lane + (((r + 1) << 3 | j) << 6)];
                online4(v, m[j], s[j]);
            }
        }
        #pragma unroll
        for (int j = 0; j < 8; j++) online4(buf[j], m[j], s[j]);

        combine_ms(m[0], s[0], m[1], s[1]);
        combine_ms(m[2], s[2], m[3], s[3]);
        combine_ms(m[4], s[4], m[5], s[5]);
        combine_ms(m[6], s[6], m[7], s[7]);
        combine_ms(m[0], s[0], m[2], s[2]);
        combine_ms(m[4], s[4], m[6], s[6]);
        combine_ms(m[0], s[0], m[4], s[4]);
        float M = m[0], S = s[0];
        #pragma unroll
        for (int off = 32; off; off >>= 1)
            combine_ms(M, S, __shfl_xor(M, off), __shfl_xor(S, off));

        if (lane == 0) ws8[row * 8 + 3] = M + hw_log2(S) * LN2 - xt;

    } else if (gw < 8192) {
        // ---------- level 2: one wave = one row of 2048 ----------
        const int row = gw - 4096;
        const float4* r2 = (const float4*)(o2 + (size_t)row * 2048);

        int tgt = 0;
        if (lane == 0) tgt = targets[row * 4 + 2];

        float4 buf[8];
        #pragma unroll
        for (int j = 0; j < 8; j++) buf[j] = r2[lane + (j << 6)];

        float xt = 0.0f;
        if (lane == 0) xt = o2[(size_t)row * 2048 + tgt];

        float pm = -FLT_MAX;
        #pragma unroll
        for (int j = 0; j < 8; j++) pm = fmaxf(pm, max4(buf[j]));
        const float M = wave_max(pm);

        float ps = 0.0f;
        #pragma unroll
        for (int j = 0; j < 8; j++) ps += sumexp4(buf[j], M);
        const float S = wave_sum(ps);

        if (lane == 0) ws8[row * 8 + 2] = M + hw_log2(S) * LN2 - xt;

    } else {
        // ---------- levels 1+0 + dependency gathers: one wave per row ----------
        const int row = gw - 8192;

        int ia = 0, ib = 0, ic = 0, id = 0;
        int t1 = 0, t0 = 0;
        if (lane == 0) {
            ia = p0[row]; ib = p1[row]; ic = p2[row]; id = p3[row];
            t1 = targets[row * 4 + 1];
            t0 = targets[row * 4 + 0];
        }

        const float4* r1 = (const float4*)(o1 + (size_t)row * 512);
        const float4* r0 = (const float4*)(o0 + (size_t)row * 128);
        float4 u0 = r1[lane];
        float4 u1 = r1[lane + 64];
        float4 w0;
        if (lane < 32) w0 = r0[lane];

        float xt1 = 0.0f, xt0 = 0.0f;
        if (lane == 0) {
            xt1 = o1[(size_t)row * 512 + t1];
            xt0 = o0[(size_t)row * 128 + t0];
            ws8[row * 8 + 4] = (v01[ia * 512  + ib] != 0) ? 1.f : 0.f;
            ws8[row * 8 + 5] = (v12[ib * 2048 + ic] != 0) ? 1.f : 0.f;
            ws8[row * 8 + 6] = (v23[ic * 8192 + id] != 0) ? 1.f : 0.f;
        }

        float pm1 = fmaxf(max4(u0), max4(u1));
        const float M1 = wave_max(pm1);
        float ps1 = sumexp4(u0, M1) + sumexp4(u1, M1);
        const float S1 = wave_sum(ps1);

        float pm0 = (lane < 32) ? max4(w0) : -FLT_MAX;
        const float M0 = wave_max(pm0);
        float ps0 = (lane < 32) ? sumexp4(w0, M0) : 0.0f;
        const float S0 = wave_sum(ps0);

        if (lane == 0) {
            ws8[row * 8 + 1] = M1 + hw_log2(S1) * LN2 - xt1;
            ws8[row * 8 + 0] = M0 + hw_log2(S0) * LN2 - xt0;
        }
    }

    // ---------- fused finalize: last block reduces all partials ----------
    __syncthreads();          // all this block's ws8 stores issued (vmcnt drained)
    __threadfence();          // release: make them device-visible
    __shared__ unsigned s_last;
    if (threadIdx.x == 0) {
        atomicCAS(cnt, 0xAAAAAAAAu, 0u);          // re-arm from poison (first arrival wins)
        s_last = (atomicAdd(cnt, 1u) == GRID - 1) ? 1u : 0u;
    }
    __syncthreads();
    if (s_last == 0) return;

    __threadfence();          // acquire: discard stale cached ws8 lines

    const int tid = threadIdx.x;
    const float4* w4 = (const float4*)ws8;
    float c0 = 0.f, c1 = 0.f, c2 = 0.f, c3 = 0.f;
    float ok0 = 0.f, ok1 = 0.f, ok2 = 0.f;
    #pragma unroll
    for (int j = 0; j < 16; j++) {
        const int row = tid + (j << 8);           // 256 threads x 16 rows
        float4 a = w4[row * 2];                   // nll0..3
        float4 b = w4[row * 2 + 1];               // ok01, ok12, ok23, pad
        c0 += a.x; c1 += a.y; c2 += a.z; c3 += a.w;
        ok0 += b.x; ok1 += b.y; ok2 += b.z;
    }

    float vals[7] = {c0, c1, c2, c3, ok0, ok1, ok2};
    #pragma unroll
    for (int q = 0; q < 7; q++) {
        #pragma unroll
        for (int off = 32; off; off >>= 1) vals[q] += __shfl_xor(vals[q], off);
    }
    __shared__ float lds[4][7];
    if ((tid & 63) == 0) {
        #pragma unroll
        for (int q = 0; q < 7; q++) lds[tid >> 6][q] = vals[q];
    }
    __syncthreads();

    if (tid == 0) {
        float res[7];
        #pragma unroll
        for (int q = 0; q < 7; q++)
            res[q] = lds[0][q] + lds[1][q] + lds[2][q] + lds[3][q];
        const float inv_b = 1.0f / (float)NB;
        const float total_ce = (res[0] + res[1] + res[2] + res[3]) * inv_b;
        float total_dep = 0.f;
        #pragma unroll
        for (int q = 4; q < 7; q++)
            total_dep += E_M1 * (((float)NB - res[q]) * inv_b);
        out[0] = 0.5f * total_ce + 0.5f * total_dep;   // ALPHA = 0.5
        out[1] = total_ce;
        out[2] = total_dep;
    }
}

extern "C" void kernel_launch(void* const* d_in, const int* in_sizes, int n_in,
                              void* d_out, int out_size, void* d_ws, size_t ws_size,
                              hipStream_t stream)
{
    const float* o0 = (const float*)d_in[0];   // 4096x128
    const float* o1 = (const float*)d_in[1];   // 4096x512
    const float* o2 = (const float*)d_in[2];   // 4096x2048
    const float* o3 = (const float*)d_in[3];   // 4096x8192
    const int* targets = (const int*)d_in[4];  // 4096x4
    const int* p0 = (const int*)d_in[5];
    const int* p1 = (const int*)d_in[6];
    const int* p2 = (const int*)d_in[7];
    const int* p3 = (const int*)d_in[8];
    const int* v01 = (const int*)d_in[9];      // 128x512
    const int* v12 = (const int*)d_in[10];     // 512x2048
    const int* v23 = (const int*)d_in[11];     // 2048x8192

    float* ws8 = (float*)d_ws;                           // 4096x8 floats
    unsigned* cnt = (unsigned*)((char*)d_ws + 131072);   // completion counter
    float* out = (float*)d_out;                          // {total, ce, dep}

    hier_loss_kernel<<<GRID, 256, 0, stream>>>(o0, o1, o2, o3, targets,
                                               p0, p1, p2, p3, v01, v12, v23,
                                               ws8, cnt, out);
}

// Round 8
// 267.814 us; speedup vs baseline: 2.4815x; 2.4815x over previous
//
#include <hip/hip_runtime.h>
#include <float.h>

// HierarchicalLoss: total = 0.5*sum_l CE(out_l, targets[:,l]) + 0.5*sum_l (e-1)*mean(1-V_l[p_l,p_{l+1}])
// R8 = R6 revert (best: 269.46 us). Wave-autonomous ce — NO __syncthreads, NO LDS:
//   blocks    0..1023: 4 waves each, one wave = one FULL level-3 row
//   blocks 1024..2047: one wave = one level-2 row
//   blocks 2048..3071: one wave = one row's level-1 + level-0 + dependency gathers
// Separate tiny finalize kernel (kernel boundary = the device-scope fence; R7
// proved per-block __threadfence on CDNA4 costs ~400 us across 3072 blocks).
// ce is structure-invariant at ~70 us: it absorbs the harness's 512 MB ws-poison
// writeback debt draining concurrently with our 178 MB read (88 MB from HBM,
// rest L3-resident per R7's FETCH_SIZE).

#define NB 4096

static constexpr float LOG2E = 1.4426950408889634f;
static constexpr float LN2   = 0.6931471805599453f;
static constexpr float E_M1  = 1.7182818284590452f;   // e - 1

__device__ __forceinline__ float hw_exp2(float x) { return __builtin_amdgcn_exp2f(x); }
__device__ __forceinline__ float hw_log2(float x) { return __builtin_amdgcn_logf(x); }

__device__ __forceinline__ float max4(float4 v) {
    return fmaxf(fmaxf(v.x, v.y), fmaxf(v.z, v.w));
}
__device__ __forceinline__ float sumexp4(float4 v, float M) {
    return hw_exp2((v.x - M) * LOG2E) + hw_exp2((v.y - M) * LOG2E)
         + hw_exp2((v.z - M) * LOG2E) + hw_exp2((v.w - M) * LOG2E);
}
__device__ __forceinline__ void online4(float4 v, float& m, float& s) {
    float mn = fmaxf(m, max4(v));
    s = s * hw_exp2((m - mn) * LOG2E) + sumexp4(v, mn);
    m = mn;
}
__device__ __forceinline__ void combine_ms(float& m, float& s, float m2, float s2) {
    float mn = fmaxf(m, m2);
    s = s * hw_exp2((m - mn) * LOG2E) + s2 * hw_exp2((m2 - mn) * LOG2E);
    m = mn;
}
__device__ __forceinline__ float wave_max(float v) {
    #pragma unroll
    for (int off = 32; off; off >>= 1) v = fmaxf(v, __shfl_xor(v, off));
    return v;
}
__device__ __forceinline__ float wave_sum(float v) {
    #pragma unroll
    for (int off = 32; off; off >>= 1) v += __shfl_xor(v, off);
    return v;
}

// ws layout: [row][8] = {nll0, nll1, nll2, nll3, ok01, ok12, ok23, pad}
__global__ __launch_bounds__(256) void ce_wave_kernel(
    const float* __restrict__ o0, const float* __restrict__ o1,
    const float* __restrict__ o2, const float* __restrict__ o3,
    const int* __restrict__ targets,
    const int* __restrict__ p0, const int* __restrict__ p1,
    const int* __restrict__ p2, const int* __restrict__ p3,
    const int* __restrict__ v01, const int* __restrict__ v12,
    const int* __restrict__ v23, float* __restrict__ ws8)
{
    const int gw   = (blockIdx.x << 2) | (threadIdx.x >> 6);  // global wave id
    const int lane = threadIdx.x & 63;

    if (gw < 4096) {
        // ---------- level 3: one wave = one row of 8192 ----------
        const int row = gw;
        const float4* r3 = (const float4*)(o3 + (size_t)row * 8192);

        int tgt = 0;
        if (lane == 0) tgt = targets[row * 4 + 3];    // starts dependent chain early

        float4 buf[8];
        #pragma unroll
        for (int j = 0; j < 8; j++) buf[j] = r3[lane + (j << 6)];

        float xt = 0.0f;
        if (lane == 0) xt = o3[(size_t)row * 8192 + tgt];

        float m[8], s[8];
        #pragma unroll
        for (int j = 0; j < 8; j++) { m[j] = -FLT_MAX; s[j] = 0.0f; }

        // rounds 0..2: consume slot j, immediately refill for next round
        #pragma unroll
        for (int r = 0; r < 3; r++) {
            #pragma unroll
            for (int j = 0; j < 8; j++) {
                float4 v = buf[j];
                buf[j] = r3[lane + (((r + 1) << 3 | j) << 6)];
                online4(v, m[j], s[j]);
            }
        }
        // final round
        #pragma unroll
        for (int j = 0; j < 8; j++) online4(buf[j], m[j], s[j]);

        // merge 8 chains (tree), then 64-lane butterfly
        combine_ms(m[0], s[0], m[1], s[1]);
        combine_ms(m[2], s[2], m[3], s[3]);
        combine_ms(m[4], s[4], m[5], s[5]);
        combine_ms(m[6], s[6], m[7], s[7]);
        combine_ms(m[0], s[0], m[2], s[2]);
        combine_ms(m[4], s[4], m[6], s[6]);
        combine_ms(m[0], s[0], m[4], s[4]);
        float M = m[0], S = s[0];
        #pragma unroll
        for (int off = 32; off; off >>= 1)
            combine_ms(M, S, __shfl_xor(M, off), __shfl_xor(S, off));

        if (lane == 0) ws8[row * 8 + 3] = M + hw_log2(S) * LN2 - xt;

    } else if (gw < 8192) {
        // ---------- level 2: one wave = one row of 2048 ----------
        const int row = gw - 4096;
        const float4* r2 = (const float4*)(o2 + (size_t)row * 2048);

        int tgt = 0;
        if (lane == 0) tgt = targets[row * 4 + 2];

        float4 buf[8];
        #pragma unroll
        for (int j = 0; j < 8; j++) buf[j] = r2[lane + (j << 6)];

        float xt = 0.0f;
        if (lane == 0) xt = o2[(size_t)row * 2048 + tgt];

        float pm = -FLT_MAX;
        #pragma unroll
        for (int j = 0; j < 8; j++) pm = fmaxf(pm, max4(buf[j]));
        const float M = wave_max(pm);

        float ps = 0.0f;
        #pragma unroll
        for (int j = 0; j < 8; j++) ps += sumexp4(buf[j], M);
        const float S = wave_sum(ps);

        if (lane == 0) ws8[row * 8 + 2] = M + hw_log2(S) * LN2 - xt;

    } else {
        // ---------- levels 1+0 + dependency gathers: one wave per row ----------
        const int row = gw - 8192;

        // gather chain first (lane 0): 2 dependent rounds over the validity tables
        int ia = 0, ib = 0, ic = 0, id = 0;
        int t1 = 0, t0 = 0;
        if (lane == 0) {
            ia = p0[row]; ib = p1[row]; ic = p2[row]; id = p3[row];
            t1 = targets[row * 4 + 1];
            t0 = targets[row * 4 + 0];
        }

        const float4* r1 = (const float4*)(o1 + (size_t)row * 512);
        const float4* r0 = (const float4*)(o0 + (size_t)row * 128);
        float4 u0 = r1[lane];
        float4 u1 = r1[lane + 64];
        float4 w0;
        if (lane < 32) w0 = r0[lane];

        float xt1 = 0.0f, xt0 = 0.0f;
        if (lane == 0) {
            xt1 = o1[(size_t)row * 512 + t1];
            xt0 = o0[(size_t)row * 128 + t0];
            ws8[row * 8 + 4] = (v01[ia * 512  + ib] != 0) ? 1.f : 0.f;
            ws8[row * 8 + 5] = (v12[ib * 2048 + ic] != 0) ? 1.f : 0.f;
            ws8[row * 8 + 6] = (v23[ic * 8192 + id] != 0) ? 1.f : 0.f;
        }

        // level 1
        float pm1 = fmaxf(max4(u0), max4(u1));
        const float M1 = wave_max(pm1);
        float ps1 = sumexp4(u0, M1) + sumexp4(u1, M1);
        const float S1 = wave_sum(ps1);

        // level 0 (lanes >= 32 contribute identity)
        float pm0 = (lane < 32) ? max4(w0) : -FLT_MAX;
        const float M0 = wave_max(pm0);
        float ps0 = (lane < 32) ? sumexp4(w0, M0) : 0.0f;
        const float S0 = wave_sum(ps0);

        if (lane == 0) {
            ws8[row * 8 + 1] = M1 + hw_log2(S1) * LN2 - xt1;
            ws8[row * 8 + 0] = M0 + hw_log2(S0) * LN2 - xt0;
        }
    }
}

// Single block: reduce 4096x8 contiguous floats -> 3 scalars. ~128 KB, few us.
__global__ __launch_bounds__(1024) void finalize_kernel(
    const float* __restrict__ ws8, float* __restrict__ out)
{
    const int tid = threadIdx.x;
    const float4* w4 = (const float4*)ws8;

    float c0 = 0.f, c1 = 0.f, c2 = 0.f, c3 = 0.f;
    float ok0 = 0.f, ok1 = 0.f, ok2 = 0.f;
    #pragma unroll
    for (int j = 0; j < 4; j++) {
        const int row = tid + j * 1024;
        float4 a = w4[row * 2];        // nll0..3
        float4 b = w4[row * 2 + 1];    // ok01, ok12, ok23, pad
        c0 += a.x; c1 += a.y; c2 += a.z; c3 += a.w;
        ok0 += b.x; ok1 += b.y; ok2 += b.z;
    }

    float vals[7] = {c0, c1, c2, c3, ok0, ok1, ok2};
    #pragma unroll
    for (int q = 0; q < 7; q++) {
        #pragma unroll
        for (int off = 32; off; off >>= 1) vals[q] += __shfl_xor(vals[q], off);
    }
    __shared__ float lds[16][7];
    if ((tid & 63) == 0) {
        #pragma unroll
        for (int q = 0; q < 7; q++) lds[tid >> 6][q] = vals[q];
    }
    __syncthreads();

    if (tid == 0) {
        float res[7];
        #pragma unroll
        for (int q = 0; q < 7; q++) {
            float t = 0.f;
            for (int w = 0; w < 16; w++) t += lds[w][q];
            res[q] = t;
        }
        const float inv_b = 1.0f / (float)NB;
        const float total_ce = (res[0] + res[1] + res[2] + res[3]) * inv_b;
        float total_dep = 0.f;
        #pragma unroll
        for (int q = 4; q < 7; q++)
            total_dep += E_M1 * (((float)NB - res[q]) * inv_b);
        out[0] = 0.5f * total_ce + 0.5f * total_dep;   // ALPHA = 0.5
        out[1] = total_ce;
        out[2] = total_dep;
    }
}

extern "C" void kernel_launch(void* const* d_in, const int* in_sizes, int n_in,
                              void* d_out, int out_size, void* d_ws, size_t ws_size,
                              hipStream_t stream)
{
    const float* o0 = (const float*)d_in[0];   // 4096x128
    const float* o1 = (const float*)d_in[1];   // 4096x512
    const float* o2 = (const float*)d_in[2];   // 4096x2048
    const float* o3 = (const float*)d_in[3];   // 4096x8192
    const int* targets = (const int*)d_in[4];  // 4096x4
    const int* p0 = (const int*)d_in[5];
    const int* p1 = (const int*)d_in[6];
    const int* p2 = (const int*)d_in[7];
    const int* p3 = (const int*)d_in[8];
    const int* v01 = (const int*)d_in[9];      // 128x512
    const int* v12 = (const int*)d_in[10];     // 512x2048
    const int* v23 = (const int*)d_in[11];     // 2048x8192

    float* ws8 = (float*)d_ws;                 // 4096x8 floats, fully rewritten each call
    float* out = (float*)d_out;                // {total, total_ce, total_dep}

    ce_wave_kernel<<<3072, 256, 0, stream>>>(o0, o1, o2, o3, targets,
                                             p0, p1, p2, p3, v01, v12, v23, ws8);
    finalize_kernel<<<1, 1024, 0, stream>>>(ws8, out);
}